// Round 8
// baseline (459.409 us; speedup 1.0000x reference)
//
#include <hip/hip_runtime.h>
#include <hip/hip_bf16.h>

#define N_NODES 100000
#define N_EDGES 3200000
#define D 64
#define NEG_SLOPE 0.01f

#define B_SHIFT 9                          // bucket = 512 nodes
#define NB ((N_NODES + 511) >> B_SHIFT)    // 196 buckets
#define BCAP 18432                         // fixed pairs capacity per bucket (>16 sigma)
#define T_EDGES 4096                       // edges per binning block
#define NBIN ((N_EDGES + T_EDGES - 1) / T_EDGES)  // 782 binning blocks

using bf16x8 = __attribute__((ext_vector_type(8))) short;   // MFMA A/B frag (4 VGPR)
using f32x4  = __attribute__((ext_vector_type(4))) float;   // MFMA C/D frag

__device__ __forceinline__ unsigned short f2bf(float f) {
    __hip_bfloat16 h = __float2bfloat16(f);
    return *reinterpret_cast<unsigned short*>(&h);
}
__device__ __forceinline__ float bflo(unsigned int u) { return __uint_as_float(u << 16); }
__device__ __forceinline__ float bfhi(unsigned int u) { return __uint_as_float(u & 0xffff0000u); }
__device__ __forceinline__ float bf2f(unsigned short h) { return __uint_as_float(((unsigned int)h) << 16); }

// ---------------- coarse placement: LDS-reorder, fixed-capacity buckets ----------
// pairs element = (src << 9) | (dst & 511), written to region [b*BCAP, b*BCAP+cnt).
// No pre-histogram needed: bcnt2 atomics reserve runs directly.
__global__ __launch_bounds__(256) void bucket_k(const int* __restrict__ src, const int* __restrict__ dst,
                                                int* __restrict__ bcnt2,
                                                unsigned* __restrict__ pairs) {
    __shared__ int hist[NB];
    __shared__ int lbase[NB];
    __shared__ int lcnt[NB];
    __shared__ int gbase[NB];           // global run base with -lbase folded in
    __shared__ int wsum[4];
    __shared__ unsigned buf[T_EDGES];   // 16 KB reorder buffer
    __shared__ unsigned char bid[T_EDGES];  // 4 KB bucket id per slot
    int tid = threadIdx.x;
    for (int b = tid; b < NB; b += 256) { hist[b] = 0; lcnt[b] = 0; }
    __syncthreads();
    int e0 = blockIdx.x * T_EDGES;
    int e1 = min(e0 + T_EDGES, N_EDGES);
    for (int e = e0 + tid; e < e1; e += 256) atomicAdd(&hist[dst[e] >> B_SHIFT], 1);
    __syncthreads();
    {
        int v = (tid < NB) ? hist[tid] : 0;
        int lane = tid & 63, w = tid >> 6;
        int incl = v;
        #pragma unroll
        for (int o = 1; o < 64; o <<= 1) {
            int u = __shfl_up(incl, o, 64);
            if (lane >= o) incl += u;
        }
        if (lane == 63) wsum[w] = incl;
        __syncthreads();
        int woff = 0;
        for (int k = 0; k < w; ++k) woff += wsum[k];
        if (tid < NB) {
            int excl = woff + incl - v;
            lbase[tid] = excl;
            int p = v ? atomicAdd(&bcnt2[tid], v) : 0;
            gbase[tid] = tid * BCAP + p - excl;   // stream-out addr = gbase[b] + i
        }
    }
    __syncthreads();
    for (int e = e0 + tid; e < e1; e += 256) {
        int sv = src[e], dv = dst[e];
        int b = dv >> B_SHIFT;
        int loc = lbase[b] + atomicAdd(&lcnt[b], 1);
        buf[loc] = ((unsigned)sv << 9) | (unsigned)(dv & 511);
        bid[loc] = (unsigned char)b;
    }
    __syncthreads();
    int n = e1 - e0;
    for (int i = tid; i < n; i += 256) {
        int b = bid[i];
        pairs[gbase[b] + i] = buf[i];
    }
}

// one-block exclusive scan over bcnt2 -> bbase[0..NB] (packed csr bucket bases)
__global__ __launch_bounds__(256) void bscan_k(const int* __restrict__ bcnt2, int* __restrict__ bbase) {
    __shared__ int wsum[4];
    int t = threadIdx.x;
    int lane = t & 63, w = t >> 6;
    int v = (t < NB) ? bcnt2[t] : 0;
    int incl = v;
    #pragma unroll
    for (int o = 1; o < 64; o <<= 1) {
        int u = __shfl_up(incl, o, 64);
        if (lane >= o) incl += u;
    }
    if (lane == 63) wsum[w] = incl;
    __syncthreads();
    int woff = 0;
    for (int k = 0; k < w; ++k) woff += wsum[k];
    if (t < NB) bbase[t] = woff + incl - v;
    if (t == NB) bbase[NB] = N_EDGES;
}

// ---------------- fine (split 2x + fused cvt): degree, scan, scatter, bf16 rows ----
// 2 blocks per bucket; each counts the whole bucket (packed reads) but scatters +
// emits degi/offs/rsd/xb only for its 256-node half. csr is packed via bbase.
__global__ __launch_bounds__(512) void fine_k(const unsigned* __restrict__ pairs,
                                              const int* __restrict__ bcnt2, const int* __restrict__ bbase,
                                              int* __restrict__ degi, int* __restrict__ offs,
                                              float* __restrict__ rsd, int* __restrict__ csr_src,
                                              const float* __restrict__ x, unsigned short* __restrict__ xb) {
    __shared__ int cnt[512];
    __shared__ int offl[512];
    __shared__ int wsum[8];
    __shared__ float rsdl[256];
    int b = blockIdx.x >> 1, half = blockIdx.x & 1, t = threadIdx.x;
    int pstart = b * BCAP;
    int pend = pstart + bcnt2[b];
    int cbase = bbase[b];
    cnt[t] = 0;
    __syncthreads();
    for (int e = pstart + t; e < pend; e += 512) atomicAdd(&cnt[pairs[e] & 511], 1);
    __syncthreads();
    int d = cnt[t];
    int lane = t & 63, w = t >> 6;
    int incl = d;
    #pragma unroll
    for (int o = 1; o < 64; o <<= 1) {
        int u = __shfl_up(incl, o, 64);
        if (lane >= o) incl += u;
    }
    if (lane == 63) wsum[w] = incl;
    __syncthreads();
    int woff = 0;
    for (int k = 0; k < w; ++k) woff += wsum[k];
    int myoff = cbase + woff + incl - d;
    offl[t] = myoff;
    int n = (b << B_SHIFT) + t;
    float rn = rsqrtf((float)(d > 0 ? d : 1));
    if ((t >> 8) == half) {
        if (n < N_NODES) {
            degi[n] = d;
            offs[n] = myoff;
            rsd[n] = rn;
        }
        rsdl[t & 255] = rn;
    }
    cnt[t] = 0;
    __syncthreads();
    for (int e = pstart + t; e < pend; e += 512) {
        unsigned pr = pairs[e];
        int li = pr & 511;
        if ((li >> 8) == half) {
            int p = atomicAdd(&cnt[li], 1);
            csr_src[offl[li] + p] = (int)(pr >> 9);
        }
    }
    __syncthreads();
    // fused cvt: bf16 rsd-prescaled rows for my 256 nodes
    int nbase = (b << B_SHIFT) + (half << 8);
    for (int i = t; i < 256 * 16; i += 512) {
        int nl = i >> 4;
        int node = nbase + nl;
        if (node < N_NODES) {
            float r = rsdl[nl];
            float4 v = ((const float4*)x)[(size_t)node * 16 + (i & 15)];
            unsigned int lo = ((unsigned int)f2bf(r * v.y) << 16) | f2bf(r * v.x);
            unsigned int hi = ((unsigned int)f2bf(r * v.w) << 16) | f2bf(r * v.z);
            ((uint2*)xb)[(size_t)node * 16 + (i & 15)] = make_uint2(lo, hi);
        }
    }
}

// ---------------- per-layer: weighted neighbor sum (bf16 gather, up to 8 in flight)
// wave per node; lane = (edge-slot g 0..7, feature-oct q 0..7), 16 B/lane.
// Per 64-edge window: ONE coalesced csr load (clamped -> all lanes valid),
// 4 gathers in flight for edges 0..31, +4 more (wave-uniform branch) if m>32.
#define ACC8(P, W) \
    acc0 += W * bflo(P.x); acc1 += W * bfhi(P.x); \
    acc2 += W * bflo(P.y); acc3 += W * bfhi(P.y); \
    acc4 += W * bflo(P.z); acc5 += W * bfhi(P.z); \
    acc6 += W * bflo(P.w); acc7 += W * bfhi(P.w);

__global__ __launch_bounds__(256) void agg_k(const unsigned short* __restrict__ xb,
                                             const float* __restrict__ rsd,
                                             const int* __restrict__ offs, const int* __restrict__ degi,
                                             const int* __restrict__ csr_src, float* __restrict__ s) {
    int node = blockIdx.x * 4 + (threadIdx.x >> 6);
    if (node >= N_NODES) return;
    int lane = threadIdx.x & 63;
    int g = lane >> 3;
    int q = lane & 7;
    int start = offs[node];
    int deg = degi[node];
    const uint4* in4 = (const uint4*)xb;        // row = 8 uint4
    float acc0 = 0.f, acc1 = 0.f, acc2 = 0.f, acc3 = 0.f;
    float acc4 = 0.f, acc5 = 0.f, acc6 = 0.f, acc7 = 0.f;
    for (int base = 0; base < deg; base += 64) {
        int m = min(deg - base, 64);                          // edges in this window
        int idxv = csr_src[start + base + min(lane, m - 1)];  // coalesced, clamped: all lanes valid
        // group A: edges 0..31 of window
        int e0 = g, e1 = 8 + g, e2 = 16 + g, e3 = 24 + g;
        int s0 = __shfl(idxv, e0, 64);
        int s1 = __shfl(idxv, e1, 64);
        int s2 = __shfl(idxv, e2, 64);
        int s3 = __shfl(idxv, e3, 64);
        uint4 p0 = in4[(size_t)s0 * 8 + q];
        uint4 p1 = in4[(size_t)s1 * 8 + q];
        uint4 p2 = in4[(size_t)s2 * 8 + q];
        uint4 p3 = in4[(size_t)s3 * 8 + q];
        float w0 = (e0 < m) ? 1.f : 0.f, w1 = (e1 < m) ? 1.f : 0.f;
        float w2 = (e2 < m) ? 1.f : 0.f, w3 = (e3 < m) ? 1.f : 0.f;
        if (m > 32) {
            // group B: edges 32..63 — issue loads before accumulating A (8 in flight)
            int e4 = 32 + g, e5 = 40 + g, e6 = 48 + g, e7 = 56 + g;
            int s4 = __shfl(idxv, e4, 64);
            int s5 = __shfl(idxv, e5, 64);
            int s6 = __shfl(idxv, e6, 64);
            int s7 = __shfl(idxv, e7, 64);
            uint4 p4 = in4[(size_t)s4 * 8 + q];
            uint4 p5 = in4[(size_t)s5 * 8 + q];
            uint4 p6 = in4[(size_t)s6 * 8 + q];
            uint4 p7 = in4[(size_t)s7 * 8 + q];
            float w4 = (e4 < m) ? 1.f : 0.f, w5 = (e5 < m) ? 1.f : 0.f;
            float w6 = (e6 < m) ? 1.f : 0.f, w7 = (e7 < m) ? 1.f : 0.f;
            ACC8(p0, w0) ACC8(p1, w1) ACC8(p2, w2) ACC8(p3, w3)
            ACC8(p4, w4) ACC8(p5, w5) ACC8(p6, w6) ACC8(p7, w7)
        } else {
            ACC8(p0, w0) ACC8(p1, w1) ACC8(p2, w2) ACC8(p3, w3)
        }
    }
    #pragma unroll
    for (int off = 8; off < 64; off <<= 1) {
        acc0 += __shfl_xor(acc0, off, 64); acc1 += __shfl_xor(acc1, off, 64);
        acc2 += __shfl_xor(acc2, off, 64); acc3 += __shfl_xor(acc3, off, 64);
        acc4 += __shfl_xor(acc4, off, 64); acc5 += __shfl_xor(acc5, off, 64);
        acc6 += __shfl_xor(acc6, off, 64); acc7 += __shfl_xor(acc7, off, 64);
    }
    if (g == 0) {
        float rn = rsd[node];
        float4 r0, r1;
        r0.x = rn * acc0; r0.y = rn * acc1; r0.z = rn * acc2; r0.w = rn * acc3;
        r1.x = rn * acc4; r1.y = rn * acc5; r1.z = rn * acc6; r1.w = rn * acc7;
        ((float4*)s)[node * 16 + q * 2]     = r0;
        ((float4*)s)[node * 16 + q * 2 + 1] = r1;
    }
}

// ---------------- per-layer: combine + GEMM on MFMA (split-precision bf16) --------
// out[n,:] = act( (in+s) @ W1 + (s*in) @ W2 ), computed as 3-term bf16 split:
// a@W ~= ah@Wh + al@Wh + ah@Wl  (residual ~2^-17 relative; f32-equivalent).
// Block = 32 rows; wave w owns cols [16w,16w+16). No LDS, no barriers.
__global__ __launch_bounds__(256) void comb_k(const float* __restrict__ in, int stride,
                                              const float* __restrict__ s,
                                              const float* __restrict__ W1, const float* __restrict__ W2,
                                              float* __restrict__ out, int act,
                                              unsigned short* __restrict__ hb, const float* __restrict__ rsd,
                                              int bfout) {
    int tid = threadIdx.x;
    int w = tid >> 6;          // wave = column-tile index
    int l = tid & 63;
    int lr = l & 15;           // A-row / B-col / D-col
    int lk = l >> 4;           // k-group (8 consecutive k per group)

    // ---- W fragments, hi/lo split (once per block; W is L2-hot) ----
    bf16x8 w1h[2], w1l[2], w2h[2], w2l[2];     // [kstep]
    #pragma unroll
    for (int s2 = 0; s2 < 2; ++s2) {
        #pragma unroll
        for (int i = 0; i < 8; ++i) {
            int k = s2 * 32 + lk * 8 + i;
            float v1 = W1[k * D + w * 16 + lr];
            float v2 = W2[k * D + w * 16 + lr];
            unsigned short h1 = f2bf(v1);
            unsigned short h2 = f2bf(v2);
            w1h[s2][i] = (short)h1; w1l[s2][i] = (short)f2bf(v1 - bf2f(h1));
            w2h[s2][i] = (short)h2; w2l[s2][i] = (short)f2bf(v2 - bf2f(h2));
        }
    }

    int n0 = blockIdx.x * 32;
    // ---- A fragments for 2 row-tiles: a = in+s (hi/lo), b = s*in (hi/lo) ----
    bf16x8 ah[2][2], al[2][2], bh[2][2], bl[2][2];   // [rowtile][kstep]
    #pragma unroll
    for (int rt = 0; rt < 2; ++rt) {
        int n = n0 + rt * 16 + lr;
        const float* ip = in + (size_t)n * stride + lk * 8;
        const float* sp = s + (size_t)n * D + lk * 8;
        #pragma unroll
        for (int s2 = 0; s2 < 2; ++s2) {
            float ia[8], sa[8];
            *(float4*)&ia[0] = *(const float4*)(ip + s2 * 32);
            *(float4*)&ia[4] = *(const float4*)(ip + s2 * 32 + 4);
            *(float4*)&sa[0] = *(const float4*)(sp + s2 * 32);
            *(float4*)&sa[4] = *(const float4*)(sp + s2 * 32 + 4);
            #pragma unroll
            for (int i = 0; i < 8; ++i) {
                float a = ia[i] + sa[i];
                float b = sa[i] * ia[i];
                unsigned short hA = f2bf(a);
                unsigned short hB = f2bf(b);
                ah[rt][s2][i] = (short)hA; al[rt][s2][i] = (short)f2bf(a - bf2f(hA));
                bh[rt][s2][i] = (short)hB; bl[rt][s2][i] = (short)f2bf(b - bf2f(hB));
            }
        }
    }

    // ---- MFMA accumulation ----
    f32x4 acc[2] = {{0.f, 0.f, 0.f, 0.f}, {0.f, 0.f, 0.f, 0.f}};
    #pragma unroll
    for (int rt = 0; rt < 2; ++rt) {
        #pragma unroll
        for (int s2 = 0; s2 < 2; ++s2) {
            acc[rt] = __builtin_amdgcn_mfma_f32_16x16x32_bf16(ah[rt][s2], w1h[s2], acc[rt], 0, 0, 0);
            acc[rt] = __builtin_amdgcn_mfma_f32_16x16x32_bf16(al[rt][s2], w1h[s2], acc[rt], 0, 0, 0);
            acc[rt] = __builtin_amdgcn_mfma_f32_16x16x32_bf16(ah[rt][s2], w1l[s2], acc[rt], 0, 0, 0);
            acc[rt] = __builtin_amdgcn_mfma_f32_16x16x32_bf16(bh[rt][s2], w2h[s2], acc[rt], 0, 0, 0);
            acc[rt] = __builtin_amdgcn_mfma_f32_16x16x32_bf16(bl[rt][s2], w2h[s2], acc[rt], 0, 0, 0);
            acc[rt] = __builtin_amdgcn_mfma_f32_16x16x32_bf16(bh[rt][s2], w2l[s2], acc[rt], 0, 0, 0);
        }
    }

    // ---- epilogue: activation, f32 out, optional bf16 next-layer rows ----
    #pragma unroll
    for (int rt = 0; rt < 2; ++rt) {
        #pragma unroll
        for (int r = 0; r < 4; ++r) {
            int n = n0 + rt * 16 + lk * 4 + r;
            float v = acc[rt][r];
            if (act) v = v >= 0.f ? v : NEG_SLOPE * v;
            out[(size_t)n * 192 + w * 16 + lr] = v;
            if (bfout) hb[(size_t)n * D + w * 16 + lr] = f2bf(rsd[n] * v);
        }
    }
}

extern "C" void kernel_launch(void* const* d_in, const int* in_sizes, int n_in,
                              void* d_out, int out_size, void* d_ws, size_t ws_size,
                              hipStream_t stream) {
    const float* x   = (const float*)d_in[0];
    const float* W1a = (const float*)d_in[1];
    const float* W2a = (const float*)d_in[2];
    const float* W1b = (const float*)d_in[3];
    const float* W2b = (const float*)d_in[4];
    const int*   src = (const int*)d_in[5];
    const int*   dst = (const int*)d_in[6];
    float* out = (float*)d_out;

    // workspace layout (~65 MB):
    //   capacity-padded pairs (NB*BCAP*4 = 14.5 MB) ALIASES the s region (25.6 MB)
    //   (pairs dead after fine_k, before the first agg writes s).
    int*   bcnt2   = (int*)d_ws;                    // NB pad 256
    int*   bbase   = bcnt2 + 256;                   // NB+1 pad 256
    int*   degi    = bbase + 256;                   // N
    int*   offs    = degi + N_NODES;                // N
    float* rsd     = (float*)(offs + N_NODES);      // N
    int*   csr_src = (int*)(rsd + N_NODES);         // E (12.8 MB)
    unsigned short* xb = (unsigned short*)(csr_src + N_EDGES);  // N*64 bf16 (12.8 MB)
    unsigned short* hb = xb + (size_t)N_NODES * D;              // N*64 bf16 (12.8 MB)
    float* s       = (float*)(hb + (size_t)N_NODES * D);        // N*D f32 (25.6 MB)
    unsigned* pairs = (unsigned*)s;                             // aliases s during prep

    hipMemsetAsync(bcnt2, 0, 256 * sizeof(int), stream);

    bucket_k<<<NBIN, 256, 0, stream>>>(src, dst, bcnt2, pairs);
    bscan_k<<<1, 256, 0, stream>>>(bcnt2, bbase);
    fine_k<<<NB * 2, 512, 0, stream>>>(pairs, bcnt2, bbase, degi, offs, rsd, csr_src, x, xb);

    int ab = (N_NODES + 3) / 4;   // wave per node
    int cbg = N_NODES / 32;       // 3125, exact

    // layer 1: h1 = lrelu(conv(x, W1a, W2a)) -> out cols [0,64), hb = rsd*h1 (bf16)
    agg_k<<<ab, 256, 0, stream>>>(xb, rsd, offs, degi, csr_src, s);
    comb_k<<<cbg, 256, 0, stream>>>(x, D, s, W1a, W2a, out + 0, 1, hb, rsd, 1);
    // layer 2: h2 = lrelu(conv(h1, W1b, W2b)) -> out cols [64,128), hb = rsd*h2 (bf16)
    agg_k<<<ab, 256, 0, stream>>>(hb, rsd, offs, degi, csr_src, s);
    comb_k<<<cbg, 256, 0, stream>>>(out + 0, 192, s, W1b, W2b, out + 64, 1, hb, rsd, 1);
    // layer 3: h3 = conv(h2, W1b, W2b) (no act) -> out cols [128,192)
    agg_k<<<ab, 256, 0, stream>>>(hb, rsd, offs, degi, csr_src, s);
    comb_k<<<cbg, 256, 0, stream>>>(out + 64, 192, s, W1b, W2b, out + 128, 0, hb, rsd, 0);
}

// Round 9
// 435.174 us; speedup vs baseline: 1.0557x; 1.0557x over previous
//
#include <hip/hip_runtime.h>
#include <hip/hip_bf16.h>

#define N_NODES 100000
#define N_EDGES 3200000
#define D 64
#define NEG_SLOPE 0.01f

#define B_SHIFT 9                          // bucket = 512 nodes
#define NB ((N_NODES + 511) >> B_SHIFT)    // 196 buckets
#define BCAP 18432                         // fixed pairs capacity per bucket (>16 sigma)
#define T_EDGES 4096                       // edges per binning block
#define NBIN ((N_EDGES + T_EDGES - 1) / T_EDGES)  // 782 binning blocks

using bf16x8 = __attribute__((ext_vector_type(8))) short;   // MFMA A/B frag (4 VGPR)
using f32x4  = __attribute__((ext_vector_type(4))) float;   // MFMA C/D frag

__device__ __forceinline__ unsigned short f2bf(float f) {
    __hip_bfloat16 h = __float2bfloat16(f);
    return *reinterpret_cast<unsigned short*>(&h);
}
__device__ __forceinline__ float bflo(unsigned int u) { return __uint_as_float(u << 16); }
__device__ __forceinline__ float bfhi(unsigned int u) { return __uint_as_float(u & 0xffff0000u); }
__device__ __forceinline__ float bf2f(unsigned short h) { return __uint_as_float(((unsigned int)h) << 16); }

// ---------------- coarse placement: LDS-reorder, fixed-capacity buckets ----------
// pairs element = (src << 9) | (dst & 511), written to region [b*BCAP, b*BCAP+cnt).
// No pre-histogram needed: bcnt2 atomics reserve runs directly.
__global__ __launch_bounds__(256) void bucket_k(const int* __restrict__ src, const int* __restrict__ dst,
                                                int* __restrict__ bcnt2,
                                                unsigned* __restrict__ pairs) {
    __shared__ int hist[NB];
    __shared__ int lbase[NB];
    __shared__ int lcnt[NB];
    __shared__ int gbase[NB];           // global run base with -lbase folded in
    __shared__ int wsum[4];
    __shared__ unsigned buf[T_EDGES];   // 16 KB reorder buffer
    __shared__ unsigned char bid[T_EDGES];  // 4 KB bucket id per slot
    int tid = threadIdx.x;
    for (int b = tid; b < NB; b += 256) { hist[b] = 0; lcnt[b] = 0; }
    __syncthreads();
    int e0 = blockIdx.x * T_EDGES;
    int e1 = min(e0 + T_EDGES, N_EDGES);
    for (int e = e0 + tid; e < e1; e += 256) atomicAdd(&hist[dst[e] >> B_SHIFT], 1);
    __syncthreads();
    {
        int v = (tid < NB) ? hist[tid] : 0;
        int lane = tid & 63, w = tid >> 6;
        int incl = v;
        #pragma unroll
        for (int o = 1; o < 64; o <<= 1) {
            int u = __shfl_up(incl, o, 64);
            if (lane >= o) incl += u;
        }
        if (lane == 63) wsum[w] = incl;
        __syncthreads();
        int woff = 0;
        for (int k = 0; k < w; ++k) woff += wsum[k];
        if (tid < NB) {
            int excl = woff + incl - v;
            lbase[tid] = excl;
            int p = v ? atomicAdd(&bcnt2[tid], v) : 0;
            gbase[tid] = tid * BCAP + p - excl;   // stream-out addr = gbase[b] + i
        }
    }
    __syncthreads();
    for (int e = e0 + tid; e < e1; e += 256) {
        int sv = src[e], dv = dst[e];
        int b = dv >> B_SHIFT;
        int loc = lbase[b] + atomicAdd(&lcnt[b], 1);
        buf[loc] = ((unsigned)sv << 9) | (unsigned)(dv & 511);
        bid[loc] = (unsigned char)b;
    }
    __syncthreads();
    int n = e1 - e0;
    for (int i = tid; i < n; i += 256) {
        int b = bid[i];
        pairs[gbase[b] + i] = buf[i];
    }
}

// one-block exclusive scan over bcnt2 -> bbase[0..NB] (packed csr bucket bases)
__global__ __launch_bounds__(256) void bscan_k(const int* __restrict__ bcnt2, int* __restrict__ bbase) {
    __shared__ int wsum[4];
    int t = threadIdx.x;
    int lane = t & 63, w = t >> 6;
    int v = (t < NB) ? bcnt2[t] : 0;
    int incl = v;
    #pragma unroll
    for (int o = 1; o < 64; o <<= 1) {
        int u = __shfl_up(incl, o, 64);
        if (lane >= o) incl += u;
    }
    if (lane == 63) wsum[w] = incl;
    __syncthreads();
    int woff = 0;
    for (int k = 0; k < w; ++k) woff += wsum[k];
    if (t < NB) bbase[t] = woff + incl - v;
    if (t == NB) bbase[NB] = N_EDGES;
}

// ---------------- fine (split 2x + fused cvt): degree, scan, scatter, bf16 rows ----
// 2 blocks per bucket; each counts the whole bucket (packed reads) but scatters +
// emits degi/offs/rsd/xb only for its 256-node half. csr is packed via bbase.
__global__ __launch_bounds__(512) void fine_k(const unsigned* __restrict__ pairs,
                                              const int* __restrict__ bcnt2, const int* __restrict__ bbase,
                                              int* __restrict__ degi, int* __restrict__ offs,
                                              float* __restrict__ rsd, int* __restrict__ csr_src,
                                              const float* __restrict__ x, unsigned short* __restrict__ xb) {
    __shared__ int cnt[512];
    __shared__ int offl[512];
    __shared__ int wsum[8];
    __shared__ float rsdl[256];
    int b = blockIdx.x >> 1, half = blockIdx.x & 1, t = threadIdx.x;
    int pstart = b * BCAP;
    int pend = pstart + bcnt2[b];
    int cbase = bbase[b];
    cnt[t] = 0;
    __syncthreads();
    for (int e = pstart + t; e < pend; e += 512) atomicAdd(&cnt[pairs[e] & 511], 1);
    __syncthreads();
    int d = cnt[t];
    int lane = t & 63, w = t >> 6;
    int incl = d;
    #pragma unroll
    for (int o = 1; o < 64; o <<= 1) {
        int u = __shfl_up(incl, o, 64);
        if (lane >= o) incl += u;
    }
    if (lane == 63) wsum[w] = incl;
    __syncthreads();
    int woff = 0;
    for (int k = 0; k < w; ++k) woff += wsum[k];
    int myoff = cbase + woff + incl - d;
    offl[t] = myoff;
    int n = (b << B_SHIFT) + t;
    float rn = rsqrtf((float)(d > 0 ? d : 1));
    if ((t >> 8) == half) {
        if (n < N_NODES) {
            degi[n] = d;
            offs[n] = myoff;
            rsd[n] = rn;
        }
        rsdl[t & 255] = rn;
    }
    cnt[t] = 0;
    __syncthreads();
    for (int e = pstart + t; e < pend; e += 512) {
        unsigned pr = pairs[e];
        int li = pr & 511;
        if ((li >> 8) == half) {
            int p = atomicAdd(&cnt[li], 1);
            csr_src[offl[li] + p] = (int)(pr >> 9);
        }
    }
    __syncthreads();
    // fused cvt: bf16 rsd-prescaled rows for my 256 nodes
    int nbase = (b << B_SHIFT) + (half << 8);
    for (int i = t; i < 256 * 16; i += 512) {
        int nl = i >> 4;
        int node = nbase + nl;
        if (node < N_NODES) {
            float r = rsdl[nl];
            float4 v = ((const float4*)x)[(size_t)node * 16 + (i & 15)];
            unsigned int lo = ((unsigned int)f2bf(r * v.y) << 16) | f2bf(r * v.x);
            unsigned int hi = ((unsigned int)f2bf(r * v.w) << 16) | f2bf(r * v.z);
            ((uint2*)xb)[(size_t)node * 16 + (i & 15)] = make_uint2(lo, hi);
        }
    }
}

// ---------------- per-layer: weighted neighbor sum (round-5 proven, 1 node/wave) --
// wave per node; lane = (edge-slot g 0..7, feature-oct q 0..7), 16 B/lane.
// Per 64-edge window: ONE coalesced csr load, indices via __shfl,
// 4 independent row-gathers in flight per iteration. VGPR 28 -> high occupancy;
// TLP (not ILP) is this kernel's latency-hiding mechanism (rounds 6 & 8 evidence).
__global__ __launch_bounds__(256) void agg_k(const unsigned short* __restrict__ xb,
                                             const float* __restrict__ rsd,
                                             const int* __restrict__ offs, const int* __restrict__ degi,
                                             const int* __restrict__ csr_src, float* __restrict__ s) {
    int node = blockIdx.x * 4 + (threadIdx.x >> 6);
    if (node >= N_NODES) return;
    int lane = threadIdx.x & 63;
    int g = lane >> 3;
    int q = lane & 7;
    int start = offs[node];
    int deg = degi[node];
    const uint4* in4 = (const uint4*)xb;        // row = 8 uint4
    float acc0 = 0.f, acc1 = 0.f, acc2 = 0.f, acc3 = 0.f;
    float acc4 = 0.f, acc5 = 0.f, acc6 = 0.f, acc7 = 0.f;
    for (int base = 0; base < deg; base += 64) {
        int m = min(deg - base, 64);                     // edges in this window
        int idxv = csr_src[start + base + min(lane, m - 1)];  // coalesced preload
        for (int j = 0; j < m; j += 32) {
            int e0 = j + g, e1 = j + 8 + g, e2 = j + 16 + g, e3 = j + 24 + g;
            bool v0 = e0 < m, v1 = e1 < m, v2 = e2 < m, v3 = e3 < m;
            int s0 = __shfl(idxv, e0, 64);
            int s1 = __shfl(idxv, v1 ? e1 : 0, 64);
            int s2 = __shfl(idxv, v2 ? e2 : 0, 64);
            int s3 = __shfl(idxv, v3 ? e3 : 0, 64);
            // 4 independent gathers in flight
            uint4 p0 = in4[(size_t)s0 * 8 + q];
            uint4 p1 = in4[(size_t)s1 * 8 + q];
            uint4 p2 = in4[(size_t)s2 * 8 + q];
            uint4 p3 = in4[(size_t)s3 * 8 + q];
            float w0 = v0 ? 1.f : 0.f, w1 = v1 ? 1.f : 0.f;
            float w2 = v2 ? 1.f : 0.f, w3 = v3 ? 1.f : 0.f;
            acc0 += w0 * bflo(p0.x); acc1 += w0 * bfhi(p0.x);
            acc2 += w0 * bflo(p0.y); acc3 += w0 * bfhi(p0.y);
            acc4 += w0 * bflo(p0.z); acc5 += w0 * bfhi(p0.z);
            acc6 += w0 * bflo(p0.w); acc7 += w0 * bfhi(p0.w);
            acc0 += w1 * bflo(p1.x); acc1 += w1 * bfhi(p1.x);
            acc2 += w1 * bflo(p1.y); acc3 += w1 * bfhi(p1.y);
            acc4 += w1 * bflo(p1.z); acc5 += w1 * bfhi(p1.z);
            acc6 += w1 * bflo(p1.w); acc7 += w1 * bfhi(p1.w);
            acc0 += w2 * bflo(p2.x); acc1 += w2 * bfhi(p2.x);
            acc2 += w2 * bflo(p2.y); acc3 += w2 * bfhi(p2.y);
            acc4 += w2 * bflo(p2.z); acc5 += w2 * bfhi(p2.z);
            acc6 += w2 * bflo(p2.w); acc7 += w2 * bfhi(p2.w);
            acc0 += w3 * bflo(p3.x); acc1 += w3 * bfhi(p3.x);
            acc2 += w3 * bflo(p3.y); acc3 += w3 * bfhi(p3.y);
            acc4 += w3 * bflo(p3.z); acc5 += w3 * bfhi(p3.z);
            acc6 += w3 * bflo(p3.w); acc7 += w3 * bfhi(p3.w);
        }
    }
    #pragma unroll
    for (int off = 8; off < 64; off <<= 1) {
        acc0 += __shfl_xor(acc0, off, 64); acc1 += __shfl_xor(acc1, off, 64);
        acc2 += __shfl_xor(acc2, off, 64); acc3 += __shfl_xor(acc3, off, 64);
        acc4 += __shfl_xor(acc4, off, 64); acc5 += __shfl_xor(acc5, off, 64);
        acc6 += __shfl_xor(acc6, off, 64); acc7 += __shfl_xor(acc7, off, 64);
    }
    if (g == 0) {
        float rn = rsd[node];
        float4 r0, r1;
        r0.x = rn * acc0; r0.y = rn * acc1; r0.z = rn * acc2; r0.w = rn * acc3;
        r1.x = rn * acc4; r1.y = rn * acc5; r1.z = rn * acc6; r1.w = rn * acc7;
        ((float4*)s)[node * 16 + q * 2]     = r0;
        ((float4*)s)[node * 16 + q * 2 + 1] = r1;
    }
}

// ---------------- per-layer: combine + GEMM on MFMA (split-precision bf16) --------
// out[n,:] = act( (in+s) @ W1 + (s*in) @ W2 ), computed as 3-term bf16 split:
// a@W ~= ah@Wh + al@Wh + ah@Wl  (residual ~2^-17 relative; f32-equivalent).
// Block = 32 rows; wave w owns cols [16w,16w+16). No LDS, no barriers.
__global__ __launch_bounds__(256) void comb_k(const float* __restrict__ in, int stride,
                                              const float* __restrict__ s,
                                              const float* __restrict__ W1, const float* __restrict__ W2,
                                              float* __restrict__ out, int act,
                                              unsigned short* __restrict__ hb, const float* __restrict__ rsd,
                                              int bfout) {
    int tid = threadIdx.x;
    int w = tid >> 6;          // wave = column-tile index
    int l = tid & 63;
    int lr = l & 15;           // A-row / B-col / D-col
    int lk = l >> 4;           // k-group (8 consecutive k per group)

    // ---- W fragments, hi/lo split (once per block; W is L2-hot) ----
    bf16x8 w1h[2], w1l[2], w2h[2], w2l[2];     // [kstep]
    #pragma unroll
    for (int s2 = 0; s2 < 2; ++s2) {
        #pragma unroll
        for (int i = 0; i < 8; ++i) {
            int k = s2 * 32 + lk * 8 + i;
            float v1 = W1[k * D + w * 16 + lr];
            float v2 = W2[k * D + w * 16 + lr];
            unsigned short h1 = f2bf(v1);
            unsigned short h2 = f2bf(v2);
            w1h[s2][i] = (short)h1; w1l[s2][i] = (short)f2bf(v1 - bf2f(h1));
            w2h[s2][i] = (short)h2; w2l[s2][i] = (short)f2bf(v2 - bf2f(h2));
        }
    }

    int n0 = blockIdx.x * 32;
    // ---- A fragments for 2 row-tiles: a = in+s (hi/lo), b = s*in (hi/lo) ----
    bf16x8 ah[2][2], al[2][2], bh[2][2], bl[2][2];   // [rowtile][kstep]
    #pragma unroll
    for (int rt = 0; rt < 2; ++rt) {
        int n = n0 + rt * 16 + lr;
        const float* ip = in + (size_t)n * stride + lk * 8;
        const float* sp = s + (size_t)n * D + lk * 8;
        #pragma unroll
        for (int s2 = 0; s2 < 2; ++s2) {
            float ia[8], sa[8];
            *(float4*)&ia[0] = *(const float4*)(ip + s2 * 32);
            *(float4*)&ia[4] = *(const float4*)(ip + s2 * 32 + 4);
            *(float4*)&sa[0] = *(const float4*)(sp + s2 * 32);
            *(float4*)&sa[4] = *(const float4*)(sp + s2 * 32 + 4);
            #pragma unroll
            for (int i = 0; i < 8; ++i) {
                float a = ia[i] + sa[i];
                float b = sa[i] * ia[i];
                unsigned short hA = f2bf(a);
                unsigned short hB = f2bf(b);
                ah[rt][s2][i] = (short)hA; al[rt][s2][i] = (short)f2bf(a - bf2f(hA));
                bh[rt][s2][i] = (short)hB; bl[rt][s2][i] = (short)f2bf(b - bf2f(hB));
            }
        }
    }

    // ---- MFMA accumulation ----
    f32x4 acc[2] = {{0.f, 0.f, 0.f, 0.f}, {0.f, 0.f, 0.f, 0.f}};
    #pragma unroll
    for (int rt = 0; rt < 2; ++rt) {
        #pragma unroll
        for (int s2 = 0; s2 < 2; ++s2) {
            acc[rt] = __builtin_amdgcn_mfma_f32_16x16x32_bf16(ah[rt][s2], w1h[s2], acc[rt], 0, 0, 0);
            acc[rt] = __builtin_amdgcn_mfma_f32_16x16x32_bf16(al[rt][s2], w1h[s2], acc[rt], 0, 0, 0);
            acc[rt] = __builtin_amdgcn_mfma_f32_16x16x32_bf16(ah[rt][s2], w1l[s2], acc[rt], 0, 0, 0);
            acc[rt] = __builtin_amdgcn_mfma_f32_16x16x32_bf16(bh[rt][s2], w2h[s2], acc[rt], 0, 0, 0);
            acc[rt] = __builtin_amdgcn_mfma_f32_16x16x32_bf16(bl[rt][s2], w2h[s2], acc[rt], 0, 0, 0);
            acc[rt] = __builtin_amdgcn_mfma_f32_16x16x32_bf16(bh[rt][s2], w2l[s2], acc[rt], 0, 0, 0);
        }
    }

    // ---- epilogue: activation, f32 out, optional bf16 next-layer rows ----
    #pragma unroll
    for (int rt = 0; rt < 2; ++rt) {
        #pragma unroll
        for (int r = 0; r < 4; ++r) {
            int n = n0 + rt * 16 + lk * 4 + r;
            float v = acc[rt][r];
            if (act) v = v >= 0.f ? v : NEG_SLOPE * v;
            out[(size_t)n * 192 + w * 16 + lr] = v;
            if (bfout) hb[(size_t)n * D + w * 16 + lr] = f2bf(rsd[n] * v);
        }
    }
}

extern "C" void kernel_launch(void* const* d_in, const int* in_sizes, int n_in,
                              void* d_out, int out_size, void* d_ws, size_t ws_size,
                              hipStream_t stream) {
    const float* x   = (const float*)d_in[0];
    const float* W1a = (const float*)d_in[1];
    const float* W2a = (const float*)d_in[2];
    const float* W1b = (const float*)d_in[3];
    const float* W2b = (const float*)d_in[4];
    const int*   src = (const int*)d_in[5];
    const int*   dst = (const int*)d_in[6];
    float* out = (float*)d_out;

    // workspace layout (~65 MB):
    //   capacity-padded pairs (NB*BCAP*4 = 14.5 MB) ALIASES the s region (25.6 MB)
    //   (pairs dead after fine_k, before the first agg writes s).
    int*   bcnt2   = (int*)d_ws;                    // NB pad 256
    int*   bbase   = bcnt2 + 256;                   // NB+1 pad 256
    int*   degi    = bbase + 256;                   // N
    int*   offs    = degi + N_NODES;                // N
    float* rsd     = (float*)(offs + N_NODES);      // N
    int*   csr_src = (int*)(rsd + N_NODES);         // E (12.8 MB)
    unsigned short* xb = (unsigned short*)(csr_src + N_EDGES);  // N*64 bf16 (12.8 MB)
    unsigned short* hb = xb + (size_t)N_NODES * D;              // N*64 bf16 (12.8 MB)
    float* s       = (float*)(hb + (size_t)N_NODES * D);        // N*D f32 (25.6 MB)
    unsigned* pairs = (unsigned*)s;                             // aliases s during prep

    hipMemsetAsync(bcnt2, 0, 256 * sizeof(int), stream);

    bucket_k<<<NBIN, 256, 0, stream>>>(src, dst, bcnt2, pairs);
    bscan_k<<<1, 256, 0, stream>>>(bcnt2, bbase);
    fine_k<<<NB * 2, 512, 0, stream>>>(pairs, bcnt2, bbase, degi, offs, rsd, csr_src, x, xb);

    int ab = (N_NODES + 3) / 4;   // wave per node
    int cbg = N_NODES / 32;       // 3125, exact

    // layer 1: h1 = lrelu(conv(x, W1a, W2a)) -> out cols [0,64), hb = rsd*h1 (bf16)
    agg_k<<<ab, 256, 0, stream>>>(xb, rsd, offs, degi, csr_src, s);
    comb_k<<<cbg, 256, 0, stream>>>(x, D, s, W1a, W2a, out + 0, 1, hb, rsd, 1);
    // layer 2: h2 = lrelu(conv(h1, W1b, W2b)) -> out cols [64,128), hb = rsd*h2 (bf16)
    agg_k<<<ab, 256, 0, stream>>>(hb, rsd, offs, degi, csr_src, s);
    comb_k<<<cbg, 256, 0, stream>>>(out + 0, 192, s, W1b, W2b, out + 64, 1, hb, rsd, 1);
    // layer 3: h3 = conv(h2, W1b, W2b) (no act) -> out cols [128,192)
    agg_k<<<ab, 256, 0, stream>>>(hb, rsd, offs, degi, csr_src, s);
    comb_k<<<cbg, 256, 0, stream>>>(out + 64, 192, s, W1b, W2b, out + 128, 0, hb, rsd, 0);
}